// Round 7
// baseline (230.157 us; speedup 1.0000x reference)
//
#include <hip/hip_runtime.h>

#define NUM_USERS 100000
#define NUM_ITEMS 100000
#define EMB_DIM   128
#define NUM_EDGES 600000
#define NN        200000   // N_NODES

#define SCAN_B  256
#define SCAN_NB ((NN + SCAN_B - 1) / SCAN_B)   // 782

#define CONV_NB 25000      // NN*EMB_DIM/4 float4-quads / 256
#define CNT_NB  ((NUM_EDGES + 255) / 256)

typedef __attribute__((ext_vector_type(8))) unsigned short ushort8_t;
typedef __attribute__((ext_vector_type(4))) float float4_t;

// bf16 helpers (RNE rounding)
__device__ inline float bf2f(unsigned short u) {
    unsigned int x = ((unsigned int)u) << 16;
    return __builtin_bit_cast(float, x);
}
__device__ inline unsigned short f2bf(float f) {
    unsigned int x = __builtin_bit_cast(unsigned int, f);
    x += 0x7fffu + ((x >> 16) & 1u);   // round-to-nearest-even
    return (unsigned short)(x >> 16);
}

// ---------- fused: emb f32 -> x0 bf16 (streaming)  ∪  degree count ----------
__global__ void k_setup(const float* __restrict__ emb, ushort* __restrict__ x0,
                        const int* __restrict__ col, int* __restrict__ deg) {
    int b = blockIdx.x;
    if (b < CONV_NB) {
        int i = b * 256 + threadIdx.x;
        const float4 v = reinterpret_cast<const float4*>(emb)[i];
        ushort4 w;
        w.x = f2bf(v.x); w.y = f2bf(v.y); w.z = f2bf(v.z); w.w = f2bf(v.w);
        reinterpret_cast<ushort4*>(x0)[i] = w;
    } else {
        int e = (b - CONV_NB) * 256 + threadIdx.x;
        if (e < NUM_EDGES) atomicAdd(&deg[col[e]], 1);
    }
}

// ---------- scan part 1 + deg_inv_sqrt fused ----------
__global__ void k_scan1(const int* __restrict__ deg, int* __restrict__ rp,
                        int* __restrict__ bsum, float* __restrict__ dis) {
    __shared__ int s[SCAN_B];
    int tid = threadIdx.x;
    int i = blockIdx.x * SCAN_B + tid;
    int v = (i < NN) ? deg[i] : 0;
    s[tid] = v;
    __syncthreads();
    for (int off = 1; off < SCAN_B; off <<= 1) {
        int t = (tid >= off) ? s[tid - off] : 0;
        __syncthreads();
        s[tid] += t;
        __syncthreads();
    }
    if (i < NN) {
        rp[i]  = s[tid] - v;                    // exclusive within block
        dis[i] = (v > 0) ? 1.0f / sqrtf((float)v) : 0.0f;
    }
    if (tid == SCAN_B - 1) bsum[blockIdx.x] = s[tid];
}

__global__ void k_scan2(int* __restrict__ bsum) {
    __shared__ int s[1024];
    int tid = threadIdx.x;
    int v = (tid < SCAN_NB) ? bsum[tid] : 0;
    s[tid] = v;
    __syncthreads();
    for (int off = 1; off < 1024; off <<= 1) {
        int t = (tid >= off) ? s[tid - off] : 0;
        __syncthreads();
        s[tid] += t;
        __syncthreads();
    }
    if (tid < SCAN_NB) bsum[tid] = s[tid] - v;
}

__global__ void k_scan3(int* __restrict__ rp, const int* __restrict__ bsum) {
    int i = blockIdx.x * SCAN_B + threadIdx.x;
    if (i < NN) rp[i] += bsum[blockIdx.x];
    if (i == 0) rp[NN] = NUM_EDGES;
}

// ---------- CSR fill, packed (src, coef) ----------
__global__ void k_fill(const int* __restrict__ row, const int* __restrict__ col,
                       const float* __restrict__ dis, const int* __restrict__ rp,
                       int* __restrict__ cursor, int2* __restrict__ csr) {
    int e = blockIdx.x * blockDim.x + threadIdx.x;
    if (e >= NUM_EDGES) return;
    int r = row[e], c = col[e];
    int p = rp[c] + atomicAdd(&cursor[c], 1);
    csr[p] = make_int2(r, __builtin_bit_cast(int, dis[r] * dis[c]));
}

// ---------- propagation layer: y = A * x (bf16), store bf16 ----------
// 16 lanes/node, ushort8 (16B)/lane; degree loop flat-unrolled x8 —
// Poisson(3) degrees: 99.6% of nodes finish in ONE iteration, 8 gathers
// in flight per thread (clamped dups hit the same cache line, near-free).
__global__ void k_gath(const ushort* __restrict__ x, const int* __restrict__ rp,
                       const int2* __restrict__ csr, ushort* __restrict__ xn) {
    int t    = blockIdx.x * blockDim.x + threadIdx.x;
    int node = t >> 4;
    int lane = t & 15;
    if (node >= NN) return;
    int beg = rp[node], end = rp[node + 1];
    float a[8] = {0, 0, 0, 0, 0, 0, 0, 0};
    const int bd = lane * 8;
    for (int k = beg; k < end; k += 8) {
        const int last = end - 1;
        int   ki[8];
        int2  ee[8];
#pragma unroll
        for (int j = 0; j < 8; ++j) ki[j] = min(k + j, last);
#pragma unroll
        for (int j = 0; j < 8; ++j) ee[j] = csr[ki[j]];
        float cc[8];
#pragma unroll
        for (int j = 0; j < 8; ++j)
            cc[j] = (k + j <= last) ? __builtin_bit_cast(float, ee[j].y) : 0.0f;
        ushort8_t vv[8];
#pragma unroll
        for (int j = 0; j < 8; ++j)
            vv[j] = *reinterpret_cast<const ushort8_t*>(x + (size_t)ee[j].x * EMB_DIM + bd);
#pragma unroll
        for (int j = 0; j < 8; ++j) {
#pragma unroll
            for (int d = 0; d < 8; ++d)
                a[d] += cc[j] * bf2f(vv[j][d]);
        }
    }
    ushort8_t w;
#pragma unroll
    for (int j = 0; j < 8; ++j) w[j] = f2bf(a[j]);
    __builtin_nontemporal_store(w,
        reinterpret_cast<ushort8_t*>(xn + (size_t)node * EMB_DIM + bd));
}

// ---------- final: y3 = A * x2;  out = (x0 + x1 + x2 + y3) * 0.25 ----------
__global__ void k_final(const ushort* __restrict__ x2, const int* __restrict__ rp,
                        const int2* __restrict__ csr,
                        const ushort* __restrict__ x0, const ushort* __restrict__ x1,
                        float* __restrict__ out) {
    int t    = blockIdx.x * blockDim.x + threadIdx.x;
    int node = t >> 4;
    int lane = t & 15;
    if (node >= NN) return;
    int beg = rp[node], end = rp[node + 1];
    float a[8] = {0, 0, 0, 0, 0, 0, 0, 0};
    const int bd = lane * 8;
    for (int k = beg; k < end; k += 8) {
        const int last = end - 1;
        int   ki[8];
        int2  ee[8];
#pragma unroll
        for (int j = 0; j < 8; ++j) ki[j] = min(k + j, last);
#pragma unroll
        for (int j = 0; j < 8; ++j) ee[j] = csr[ki[j]];
        float cc[8];
#pragma unroll
        for (int j = 0; j < 8; ++j)
            cc[j] = (k + j <= last) ? __builtin_bit_cast(float, ee[j].y) : 0.0f;
        ushort8_t vv[8];
#pragma unroll
        for (int j = 0; j < 8; ++j)
            vv[j] = *reinterpret_cast<const ushort8_t*>(x2 + (size_t)ee[j].x * EMB_DIM + bd);
#pragma unroll
        for (int j = 0; j < 8; ++j) {
#pragma unroll
            for (int d = 0; d < 8; ++d)
                a[d] += cc[j] * bf2f(vv[j][d]);
        }
    }
    const size_t o = (size_t)node * EMB_DIM + bd;
    // single-use coalesced reads: nontemporal, keep L2 for the gather
    const ushort8_t w0 =
        __builtin_nontemporal_load(reinterpret_cast<const ushort8_t*>(x0 + o));
    const ushort8_t w1 =
        __builtin_nontemporal_load(reinterpret_cast<const ushort8_t*>(x1 + o));
    const ushort8_t w2 = *reinterpret_cast<const ushort8_t*>(x2 + o);
    float4_t r0, r1;
#pragma unroll
    for (int j = 0; j < 4; ++j)
        r0[j] = (bf2f(w0[j]) + bf2f(w1[j]) + bf2f(w2[j]) + a[j]) * 0.25f;
#pragma unroll
    for (int j = 0; j < 4; ++j)
        r1[j] = (bf2f(w0[j + 4]) + bf2f(w1[j + 4]) + bf2f(w2[j + 4]) + a[j + 4]) * 0.25f;
    __builtin_nontemporal_store(r0, reinterpret_cast<float4_t*>(out + o));
    __builtin_nontemporal_store(r1, reinterpret_cast<float4_t*>(out + o) + 1);
}

extern "C" void kernel_launch(void* const* d_in, const int* in_sizes, int n_in,
                              void* d_out, int out_size, void* d_ws, size_t ws_size,
                              hipStream_t stream) {
    const int*   edges = (const int*)d_in[0];
    const int*   row   = edges;               // edge_index[0]
    const int*   col   = edges + NUM_EDGES;   // edge_index[1]
    const float* emb   = (const float*)d_in[1];
    float*       out   = (float*)d_out;

    char*  ws  = (char*)d_ws;
    size_t off = 0;
    auto alloc = [&](size_t bytes) {
        void* p = ws + off;
        off += (bytes + 255) & ~(size_t)255;
        return p;
    };
    ushort* x0     = (ushort*)alloc(sizeof(ushort) * (size_t)NN * EMB_DIM); // 51.2 MB
    ushort* x1     = (ushort*)alloc(sizeof(ushort) * (size_t)NN * EMB_DIM); // 51.2 MB
    ushort* x2     = (ushort*)alloc(sizeof(ushort) * (size_t)NN * EMB_DIM); // 51.2 MB
    int*    deg    = (int*)   alloc(sizeof(int)   * NN);        // deg+cursor adjacent:
    int*    cursor = (int*)   alloc(sizeof(int)   * NN);        // single memset below
    float*  dis    = (float*) alloc(sizeof(float) * NN);
    int*    rp     = (int*)   alloc(sizeof(int)   * (NN + 1));
    int2*   csr    = (int2*)  alloc(sizeof(int2)  * NUM_EDGES);             // 4.8 MB
    int*    bsum   = (int*)   alloc(sizeof(int)   * 1024);

    (void)hipMemsetAsync(deg, 0, sizeof(int) * NN * 2, stream);  // deg + cursor

    k_setup<<<CONV_NB + CNT_NB, 256, 0, stream>>>(emb, x0, col, deg);
    k_scan1<<<SCAN_NB, SCAN_B, 0, stream>>>(deg, rp, bsum, dis);
    k_scan2<<<1, 1024, 0, stream>>>(bsum);
    k_scan3<<<SCAN_NB, SCAN_B, 0, stream>>>(rp, bsum);
    k_fill<<<CNT_NB, 256, 0, stream>>>(row, col, dis, rp, cursor, csr);

    const int LB = (int)(((size_t)NN * 16) / 256);            // 12500
    k_gath <<<LB, 256, 0, stream>>>(x0, rp, csr, x1);
    k_gath <<<LB, 256, 0, stream>>>(x1, rp, csr, x2);
    k_final<<<LB, 256, 0, stream>>>(x2, rp, csr, x0, x1, out);
}

// Round 8
// 221.677 us; speedup vs baseline: 1.0383x; 1.0383x over previous
//
#include <hip/hip_runtime.h>

#define NUM_USERS 100000
#define NUM_ITEMS 100000
#define EMB_DIM   128
#define NUM_EDGES 600000
#define NN        200000   // N_NODES

#define SCAN_B  256
#define SCAN_NB ((NN + SCAN_B - 1) / SCAN_B)   // 782

#define CONV_NB 25000      // NN*EMB_DIM/4 float4-quads / 256
#define CNT_NB  ((NUM_EDGES + 255) / 256)

typedef __attribute__((ext_vector_type(8))) unsigned short ushort8_t;
typedef __attribute__((ext_vector_type(4))) float float4_t;

// bf16 helpers (RNE rounding)
__device__ inline float bf2f(unsigned short u) {
    unsigned int x = ((unsigned int)u) << 16;
    return __builtin_bit_cast(float, x);
}
__device__ inline unsigned short f2bf(float f) {
    unsigned int x = __builtin_bit_cast(unsigned int, f);
    x += 0x7fffu + ((x >> 16) & 1u);   // round-to-nearest-even
    return (unsigned short)(x >> 16);
}

// ---------- fused: emb f32 -> x0 bf16 (streaming)  ∪  degree count ----------
__global__ void k_setup(const float* __restrict__ emb, ushort* __restrict__ x0,
                        const int* __restrict__ col, int* __restrict__ deg) {
    int b = blockIdx.x;
    if (b < CONV_NB) {
        int i = b * 256 + threadIdx.x;
        const float4 v = reinterpret_cast<const float4*>(emb)[i];
        ushort4 w;
        w.x = f2bf(v.x); w.y = f2bf(v.y); w.z = f2bf(v.z); w.w = f2bf(v.w);
        reinterpret_cast<ushort4*>(x0)[i] = w;
    } else {
        int e = (b - CONV_NB) * 256 + threadIdx.x;
        if (e < NUM_EDGES) atomicAdd(&deg[col[e]], 1);
    }
}

// ---------- scan part 1 + deg_inv_sqrt fused ----------
__global__ void k_scan1(const int* __restrict__ deg, int* __restrict__ rp,
                        int* __restrict__ bsum, float* __restrict__ dis) {
    __shared__ int s[SCAN_B];
    int tid = threadIdx.x;
    int i = blockIdx.x * SCAN_B + tid;
    int v = (i < NN) ? deg[i] : 0;
    s[tid] = v;
    __syncthreads();
    for (int off = 1; off < SCAN_B; off <<= 1) {
        int t = (tid >= off) ? s[tid - off] : 0;
        __syncthreads();
        s[tid] += t;
        __syncthreads();
    }
    if (i < NN) {
        rp[i]  = s[tid] - v;                    // exclusive within block
        dis[i] = (v > 0) ? 1.0f / sqrtf((float)v) : 0.0f;
    }
    if (tid == SCAN_B - 1) bsum[blockIdx.x] = s[tid];
}

__global__ void k_scan2(int* __restrict__ bsum) {
    __shared__ int s[1024];
    int tid = threadIdx.x;
    int v = (tid < SCAN_NB) ? bsum[tid] : 0;
    s[tid] = v;
    __syncthreads();
    for (int off = 1; off < 1024; off <<= 1) {
        int t = (tid >= off) ? s[tid - off] : 0;
        __syncthreads();
        s[tid] += t;
        __syncthreads();
    }
    if (tid < SCAN_NB) bsum[tid] = s[tid] - v;
}

__global__ void k_scan3(int* __restrict__ rp, const int* __restrict__ bsum) {
    int i = blockIdx.x * SCAN_B + threadIdx.x;
    if (i < NN) rp[i] += bsum[blockIdx.x];
    if (i == 0) rp[NN] = NUM_EDGES;
}

// ---------- CSR fill, packed (src, coef) ----------
__global__ void k_fill(const int* __restrict__ row, const int* __restrict__ col,
                       const float* __restrict__ dis, const int* __restrict__ rp,
                       int* __restrict__ cursor, int2* __restrict__ csr) {
    int e = blockIdx.x * blockDim.x + threadIdx.x;
    if (e >= NUM_EDGES) return;
    int r = row[e], c = col[e];
    int p = rp[c] + atomicAdd(&cursor[c], 1);
    csr[p] = make_int2(r, __builtin_bit_cast(int, dis[r] * dis[c]));
}

// ---------- propagation layer: y = A * x (bf16), store bf16 ----------
// 8 lanes/node, 32B/lane (2x ushort8); 4-wide edge unroll -> 8 independent
// 16B gathers in flight per thread (matches k_final's measured ILP).
// Plain stores: x1/x2 are re-read by the next kernel (keep L2/L3-resident).
__global__ void k_gath(const ushort* __restrict__ x, const int* __restrict__ rp,
                       const int2* __restrict__ csr, ushort* __restrict__ xn) {
    int t    = blockIdx.x * blockDim.x + threadIdx.x;
    int node = t >> 3;
    int lane = t & 7;
    if (node >= NN) return;
    int beg = rp[node], end = rp[node + 1];
    float a[16] = {0};
    const int bd = lane * 16;
    for (int k = beg; k < end; k += 4) {
        const int last = end - 1;
        const int k1 = min(k + 1, last), k2 = min(k + 2, last), k3 = min(k + 3, last);
        const int2 e0 = csr[k], e1 = csr[k1], e2 = csr[k2], e3 = csr[k3];
        const float c0 = __builtin_bit_cast(float, e0.y);
        const float c1 = (k + 1 <= last) ? __builtin_bit_cast(float, e1.y) : 0.0f;
        const float c2 = (k + 2 <= last) ? __builtin_bit_cast(float, e2.y) : 0.0f;
        const float c3 = (k + 3 <= last) ? __builtin_bit_cast(float, e3.y) : 0.0f;
        const ushort* p0 = x + (size_t)e0.x * EMB_DIM + bd;
        const ushort* p1 = x + (size_t)e1.x * EMB_DIM + bd;
        const ushort* p2 = x + (size_t)e2.x * EMB_DIM + bd;
        const ushort* p3 = x + (size_t)e3.x * EMB_DIM + bd;
        const ushort8_t v0a = *reinterpret_cast<const ushort8_t*>(p0);
        const ushort8_t v1a = *reinterpret_cast<const ushort8_t*>(p1);
        const ushort8_t v2a = *reinterpret_cast<const ushort8_t*>(p2);
        const ushort8_t v3a = *reinterpret_cast<const ushort8_t*>(p3);
        const ushort8_t v0b = *reinterpret_cast<const ushort8_t*>(p0 + 8);
        const ushort8_t v1b = *reinterpret_cast<const ushort8_t*>(p1 + 8);
        const ushort8_t v2b = *reinterpret_cast<const ushort8_t*>(p2 + 8);
        const ushort8_t v3b = *reinterpret_cast<const ushort8_t*>(p3 + 8);
#pragma unroll
        for (int j = 0; j < 8; ++j) {
            a[j]     += c0 * bf2f(v0a[j]) + c1 * bf2f(v1a[j]) +
                        c2 * bf2f(v2a[j]) + c3 * bf2f(v3a[j]);
            a[j + 8] += c0 * bf2f(v0b[j]) + c1 * bf2f(v1b[j]) +
                        c2 * bf2f(v2b[j]) + c3 * bf2f(v3b[j]);
        }
    }
    ushort8_t wa, wb;
#pragma unroll
    for (int j = 0; j < 8; ++j) { wa[j] = f2bf(a[j]); wb[j] = f2bf(a[j + 8]); }
    ushort* q = xn + (size_t)node * EMB_DIM + bd;
    *reinterpret_cast<ushort8_t*>(q)     = wa;
    *reinterpret_cast<ushort8_t*>(q + 8) = wb;
}

// ---------- final: y3 = A * x2;  out = (x0 + x1 + x2 + y3) * 0.25 ----------
// (R5's proven form: 16 lanes/node, 4-wide unroll, NT store for out only)
__global__ void k_final(const ushort* __restrict__ x2, const int* __restrict__ rp,
                        const int2* __restrict__ csr,
                        const ushort* __restrict__ x0, const ushort* __restrict__ x1,
                        float* __restrict__ out) {
    int t    = blockIdx.x * blockDim.x + threadIdx.x;
    int node = t >> 4;
    int lane = t & 15;
    if (node >= NN) return;
    int beg = rp[node], end = rp[node + 1];
    float a[8] = {0, 0, 0, 0, 0, 0, 0, 0};
    const int bd = lane * 8;
    for (int k = beg; k < end; k += 4) {
        const int last = end - 1;
        const int k1 = min(k + 1, last), k2 = min(k + 2, last), k3 = min(k + 3, last);
        const int2 e0 = csr[k], e1 = csr[k1], e2 = csr[k2], e3 = csr[k3];
        const float c0 = __builtin_bit_cast(float, e0.y);
        const float c1 = (k + 1 <= last) ? __builtin_bit_cast(float, e1.y) : 0.0f;
        const float c2 = (k + 2 <= last) ? __builtin_bit_cast(float, e2.y) : 0.0f;
        const float c3 = (k + 3 <= last) ? __builtin_bit_cast(float, e3.y) : 0.0f;
        const ushort8_t v0 = *reinterpret_cast<const ushort8_t*>(x2 + (size_t)e0.x * EMB_DIM + bd);
        const ushort8_t v1 = *reinterpret_cast<const ushort8_t*>(x2 + (size_t)e1.x * EMB_DIM + bd);
        const ushort8_t v2 = *reinterpret_cast<const ushort8_t*>(x2 + (size_t)e2.x * EMB_DIM + bd);
        const ushort8_t v3 = *reinterpret_cast<const ushort8_t*>(x2 + (size_t)e3.x * EMB_DIM + bd);
#pragma unroll
        for (int j = 0; j < 8; ++j)
            a[j] += c0 * bf2f(v0[j]) + c1 * bf2f(v1[j]) +
                    c2 * bf2f(v2[j]) + c3 * bf2f(v3[j]);
    }
    const size_t o = (size_t)node * EMB_DIM + bd;
    const ushort8_t w0 = *reinterpret_cast<const ushort8_t*>(x0 + o);
    const ushort8_t w1 = *reinterpret_cast<const ushort8_t*>(x1 + o);
    const ushort8_t w2 = *reinterpret_cast<const ushort8_t*>(x2 + o);
    float4_t r0, r1;
#pragma unroll
    for (int j = 0; j < 4; ++j)
        r0[j] = (bf2f(w0[j]) + bf2f(w1[j]) + bf2f(w2[j]) + a[j]) * 0.25f;
#pragma unroll
    for (int j = 0; j < 4; ++j)
        r1[j] = (bf2f(w0[j + 4]) + bf2f(w1[j + 4]) + bf2f(w2[j + 4]) + a[j + 4]) * 0.25f;
    // out is never re-read: nontemporal keeps x0/x1/x2 L3-resident for the gather
    __builtin_nontemporal_store(r0, reinterpret_cast<float4_t*>(out + o));
    __builtin_nontemporal_store(r1, reinterpret_cast<float4_t*>(out + o) + 1);
}

extern "C" void kernel_launch(void* const* d_in, const int* in_sizes, int n_in,
                              void* d_out, int out_size, void* d_ws, size_t ws_size,
                              hipStream_t stream) {
    const int*   edges = (const int*)d_in[0];
    const int*   row   = edges;               // edge_index[0]
    const int*   col   = edges + NUM_EDGES;   // edge_index[1]
    const float* emb   = (const float*)d_in[1];
    float*       out   = (float*)d_out;

    char*  ws  = (char*)d_ws;
    size_t off = 0;
    auto alloc = [&](size_t bytes) {
        void* p = ws + off;
        off += (bytes + 255) & ~(size_t)255;
        return p;
    };
    ushort* x0     = (ushort*)alloc(sizeof(ushort) * (size_t)NN * EMB_DIM); // 51.2 MB
    ushort* x1     = (ushort*)alloc(sizeof(ushort) * (size_t)NN * EMB_DIM); // 51.2 MB
    ushort* x2     = (ushort*)alloc(sizeof(ushort) * (size_t)NN * EMB_DIM); // 51.2 MB
    int*    deg    = (int*)   alloc(sizeof(int)   * NN);        // deg+cursor adjacent:
    int*    cursor = (int*)   alloc(sizeof(int)   * NN);        // single memset below
    float*  dis    = (float*) alloc(sizeof(float) * NN);
    int*    rp     = (int*)   alloc(sizeof(int)   * (NN + 1));
    int2*   csr    = (int2*)  alloc(sizeof(int2)  * NUM_EDGES);             // 4.8 MB
    int*    bsum   = (int*)   alloc(sizeof(int)   * 1024);

    (void)hipMemsetAsync(deg, 0, sizeof(int) * NN * 2, stream);  // deg + cursor

    k_setup<<<CONV_NB + CNT_NB, 256, 0, stream>>>(emb, x0, col, deg);
    k_scan1<<<SCAN_NB, SCAN_B, 0, stream>>>(deg, rp, bsum, dis);
    k_scan2<<<1, 1024, 0, stream>>>(bsum);
    k_scan3<<<SCAN_NB, SCAN_B, 0, stream>>>(rp, bsum);
    k_fill<<<CNT_NB, 256, 0, stream>>>(row, col, dis, rp, cursor, csr);

    const int GB = (int)(((size_t)NN * 8)  / 256);            // 6250 (8 lanes/node)
    const int FB = (int)(((size_t)NN * 16) / 256);            // 12500 (16 lanes/node)
    k_gath <<<GB, 256, 0, stream>>>(x0, rp, csr, x1);
    k_gath <<<GB, 256, 0, stream>>>(x1, rp, csr, x2);
    k_final<<<FB, 256, 0, stream>>>(x2, rp, csr, x0, x1, out);
}